// Round 6
// baseline (234.192 us; speedup 1.0000x reference)
//
#include <hip/hip_runtime.h>

typedef _Float16 half8 __attribute__((ext_vector_type(8)));
typedef _Float16 half4 __attribute__((ext_vector_type(4)));
typedef _Float16 half2v __attribute__((ext_vector_type(2)));
typedef float f32x4 __attribute__((ext_vector_type(4)));

#define B_    16
#define N_    1024
#define D_    768
#define H_    12
#define M_    (B_ * N_)     // 16384
#define QKVN_ 2304
#define EPS_  1e-5f
#define QS_   0.18033688011112042f   // 0.125 * log2(e): folds softmax scale + exp->exp2

__device__ __forceinline__ float exp2_fast(float x) {
#if __has_builtin(__builtin_amdgcn_exp2f)
    return __builtin_amdgcn_exp2f(x);
#else
    return __builtin_exp2f(x);
#endif
}

__device__ __forceinline__ void gl16(const _Float16* g, _Float16* l) {
    __builtin_amdgcn_global_load_lds((const __attribute__((address_space(1))) void*)g,
                                     (__attribute__((address_space(3))) void*)l, 16, 0, 0);
}

// ---------------- weight transpose + f32->f16 cast (LDS-tiled, coalesced) ----------------
__global__ __launch_bounds__(256) void convert_w(const float* __restrict__ Wqkv,
                                                 const float* __restrict__ Wproj,
                                                 _Float16* __restrict__ wqkvT,
                                                 _Float16* __restrict__ wprojT) {
    __shared__ float T[64][65];
    int t = blockIdx.x;
    const float* W; _Float16* O; int NW, k0, n0;
    if (t < 432) { W = Wqkv;  O = wqkvT;  NW = QKVN_; k0 = (t % 12) * 64; n0 = (t / 12) * 64; }
    else { t -= 432; W = Wproj; O = wprojT; NW = D_;  k0 = (t % 12) * 64; n0 = (t / 12) * 64; }
    int c = threadIdx.x & 63, r4 = threadIdx.x >> 6;
#pragma unroll
    for (int i = 0; i < 16; ++i) {
        int r = i * 4 + r4;
        T[r][c] = W[(size_t)(k0 + r) * NW + n0 + c];
    }
    __syncthreads();
#pragma unroll
    for (int i = 0; i < 16; ++i) {
        int r = i * 4 + r4;
        O[(size_t)(n0 + r) * D_ + k0 + c] = (_Float16)T[c][r];
    }
}

// ---------------- embed LayerNorm: x f32 [16384][768] -> xn f16 (float2/half2) -------------
__global__ __launch_bounds__(256) void ln_embed(const float* __restrict__ x,
                                                const float* __restrict__ g,
                                                const float* __restrict__ bb,
                                                _Float16* __restrict__ xn) {
    int row = blockIdx.x;
    int tid = threadIdx.x;
    const float2* xr = (const float2*)(x + (size_t)row * D_);   // 384 float2
    float2 v0 = xr[tid];
    float2 v1 = make_float2(0.f, 0.f);
    if (tid < 128) v1 = xr[256 + tid];
    float s = v0.x + v0.y + v1.x + v1.y;
    float q = v0.x * v0.x + v0.y * v0.y + v1.x * v1.x + v1.y * v1.y;
#pragma unroll
    for (int m = 32; m >= 1; m >>= 1) {
        s += __shfl_xor(s, m);
        q += __shfl_xor(q, m);
    }
    __shared__ float ss[4], qq[4];
    int wave = tid >> 6;
    if ((tid & 63) == 0) { ss[wave] = s; qq[wave] = q; }
    __syncthreads();
    float S = ss[0] + ss[1] + ss[2] + ss[3];
    float Q = qq[0] + qq[1] + qq[2] + qq[3];
    float mean = S * (1.f / 768.f);
    float var  = Q * (1.f / 768.f) - mean * mean;
    float rstd = rsqrtf(var + EPS_);
    const float2* g2 = (const float2*)g;
    const float2* b2 = (const float2*)bb;
    half2v* xo = (half2v*)(xn + (size_t)row * D_);
    {
        float2 ga = g2[tid], ba = b2[tid];
        half2v w;
        w[0] = (_Float16)((v0.x - mean) * rstd * ga.x + ba.x);
        w[1] = (_Float16)((v0.y - mean) * rstd * ga.y + ba.y);
        xo[tid] = w;
    }
    if (tid < 128) {
        float2 ga = g2[256 + tid], ba = b2[256 + tid];
        half2v w;
        w[0] = (_Float16)((v1.x - mean) * rstd * ga.x + ba.x);
        w[1] = (_Float16)((v1.y - mean) * rstd * ga.y + ba.y);
        xo[256 + tid] = w;
    }
}

// ---------------- QKV GEMM + fused per-head LN + fragment-major scatter ----------------
// Ring-3 LDS + counted vmcnt (T4): loads stay 2 K-steps in flight across raw
// s_barriers; NO vmcnt(0) drain in the loop. Tail kept uniform by wrapped
// (redundant) stages. L2 block order: XCD x owns m-panels [16x,16x+16), n fastest.
__global__ __launch_bounds__(256) void gemm_qkv(const _Float16* __restrict__ A,
                                                const _Float16* __restrict__ BT,
                                                const float* __restrict__ bias,
                                                const float* __restrict__ qn_g,
                                                const float* __restrict__ qn_b,
                                                const float* __restrict__ kn_g,
                                                const float* __restrict__ kn_b,
                                                _Float16* __restrict__ qo,
                                                _Float16* __restrict__ ko,
                                                _Float16* __restrict__ vt) {
    __shared__ _Float16 As[3][128 * 32];
    __shared__ _Float16 Bs[3][128 * 32];
    const int K = D_;
    int xcd = blockIdx.x & 7, loc = blockIdx.x >> 3;     // 2304 = 8 XCD * (16 m * 18 n)
    int m0 = (xcd * 16 + loc / 18) * 128;
    int n0 = (loc % 18) * 128;
    int tid = threadIdx.x;
    int wave = tid >> 6, lane = tid & 63;
    int wm = wave >> 1, wn = wave & 1;
    int lg = lane >> 4, l15 = lane & 15;
    int xorr = (l15 >> 1) & 3;

    auto stage = [&](int buf, int tstep) {               // 4 gl16 per wave
        int k0 = tstep * 32;
#pragma unroll
        for (int i = 0; i < 2; ++i) {
            int cb = (i * 4 + wave) * 64;
            int chunk = cb + lane;
            int r = chunk >> 2, c = chunk & 3;
            int cg = c ^ ((r >> 1) & 3);
            gl16(&A[(size_t)(m0 + r) * K + k0 + cg * 8], &As[buf][cb * 8]);
            gl16(&BT[(size_t)(n0 + r) * K + k0 + cg * 8], &Bs[buf][cb * 8]);
        }
    };

    f32x4 acc[4][4] = {};
    stage(0, 0); stage(1, 1); stage(2, 2);               // 12 loads/wave in flight
    for (int t = 0; t < 24; ++t) {
        int cur = t % 3;
        asm volatile("s_waitcnt vmcnt(8)" ::: "memory"); // oldest stage (4 loads) retired
        __builtin_amdgcn_s_barrier();                    // => buf[cur] complete for ALL waves
        const _Float16* asb = As[cur];
        const _Float16* bsb = Bs[cur];
        half8 af[4], bf[4];
#pragma unroll
        for (int i = 0; i < 4; ++i) {
            af[i] = *(const half8*)&asb[(wm * 64 + i * 16 + l15) * 32 + (lg ^ xorr) * 8];
            bf[i] = *(const half8*)&bsb[(wn * 64 + i * 16 + l15) * 32 + (lg ^ xorr) * 8];
        }
#pragma unroll
        for (int mi = 0; mi < 4; ++mi)
#pragma unroll
            for (int ni = 0; ni < 4; ++ni)
                acc[mi][ni] = __builtin_amdgcn_mfma_f32_16x16x32_f16(af[mi], bf[ni], acc[mi][ni], 0, 0, 0);
        __builtin_amdgcn_sched_barrier(0);               // pin reads/MFMA before release
        __builtin_amdgcn_s_barrier();                    // all waves done reading buf[cur]
        stage(cur, (t + 3) % 24);                        // wrap => uniform vmcnt, no drain
    }

    int col0 = n0 + wn * 64;
    int s = col0 / 768;
    int hcol = (col0 % 768) >> 6;
    float qkvb[4];
#pragma unroll
    for (int ni = 0; ni < 4; ++ni) qkvb[ni] = bias[col0 + ni * 16 + l15];

    if (s == 2) {
        // V: fragment-major scatter, half4 per (mi,ni)
#pragma unroll
        for (int mi = 0; mi < 4; ++mi) {
            int r0 = m0 + wm * 64 + mi * 16 + lg * 4;
            int bidx = r0 >> 10, pos = r0 & 1023;
            int kvblk = pos >> 5, h = (pos >> 4) & 1, lgR = (pos >> 2) & 3;
            size_t vbase = ((size_t)(bidx * H_ + hcol) * 32 + kvblk) * 4;
#pragma unroll
            for (int ni = 0; ni < 4; ++ni) {
                half4 h4;
#pragma unroll
                for (int j = 0; j < 4; ++j) h4[j] = (_Float16)(acc[mi][ni][j] + qkvb[ni]);
                *(half4*)&vt[(vbase + ni) * 512 + lgR * 128 + l15 * 8 + h * 4] = h4;
            }
        }
    } else {
        const float* gg = (s == 0) ? qn_g : kn_g;
        const float* bb = (s == 0) ? qn_b : kn_b;
        float gv[4], bv[4];
#pragma unroll
        for (int ni = 0; ni < 4; ++ni) { gv[ni] = gg[ni * 16 + l15]; bv[ni] = bb[ni * 16 + l15]; }
#pragma unroll
        for (int mi = 0; mi < 4; ++mi) {
#pragma unroll
            for (int j = 0; j < 4; ++j) {
                float v[4];
                float sm = 0.f, sq = 0.f;
#pragma unroll
                for (int ni = 0; ni < 4; ++ni) {
                    v[ni] = acc[mi][ni][j] + qkvb[ni];
                    sm += v[ni];
                    sq += v[ni] * v[ni];
                }
#pragma unroll
                for (int msk = 1; msk < 16; msk <<= 1) {
                    sm += __shfl_xor(sm, msk);
                    sq += __shfl_xor(sq, msk);
                }
                float mean = sm * (1.f / 64.f);
                float var  = sq * (1.f / 64.f) - mean * mean;
                float rstd = rsqrtf(var + EPS_);
                int row = m0 + wm * 64 + mi * 16 + lg * 4 + j;
                int bidx = row >> 10, pos = row & 1023;
                if (s == 0) {
                    size_t rbase = ((size_t)(bidx * H_ + hcol) * 1024 + pos) * 64;
#pragma unroll
                    for (int ni = 0; ni < 4; ++ni) {
                        float o = (v[ni] - mean) * rstd * gv[ni] + bv[ni];
                        qo[rbase + ni * 16 + l15] = (_Float16)(o * QS_);
                    }
                } else {
                    int kvblk = pos >> 5, nh = (pos >> 4) & 1, l15R = pos & 15;
                    size_t base2 = ((size_t)(bidx * H_ + hcol) * 32 + kvblk) * 4 + nh * 2;
#pragma unroll
                    for (int ni = 0; ni < 4; ++ni) {
                        float o = (v[ni] - mean) * rstd * gv[ni] + bv[ni];
                        int ks = ni >> 1, lgR = ((ni & 1) << 1) | (l15 >> 3), elem = l15 & 7;
                        ko[(base2 + ks) * 512 + lgR * 128 + l15R * 8 + elem] = (_Float16)o;
                    }
                }
            }
        }
    }
}

// ---------------- flash attention: pure-register, fully-coalesced fragment loads ----------
struct KV {
    half8 kf[2][2];   // [nh][ks]
    half8 vf[4];      // [di]
};

__device__ __forceinline__ void ldKV(KV& s, const _Float16* kp, const _Float16* vp, int kvblk) {
    const _Float16* kb = kp + (size_t)kvblk * 2048;
#pragma unroll
    for (int nh = 0; nh < 2; ++nh)
#pragma unroll
        for (int ks = 0; ks < 2; ++ks)
            s.kf[nh][ks] = *(const half8*)(kb + (nh * 2 + ks) * 512);
    const _Float16* vb = vp + (size_t)kvblk * 2048;
#pragma unroll
    for (int di = 0; di < 4; ++di)
        s.vf[di] = *(const half8*)(vb + di * 512);
}

__device__ __forceinline__ void blockKV(const KV& s, const half8 (&qf)[4][2],
                                        f32x4 (&oacc)[4][4], f32x4 (&lacc)[4],
                                        half8 ones) {
#pragma unroll
    for (int mi = 0; mi < 4; ++mi) {
        f32x4 a0 = {}, a1 = {};
#pragma unroll
        for (int ks = 0; ks < 2; ++ks) {
            a0 = __builtin_amdgcn_mfma_f32_16x16x32_f16(s.kf[0][ks], qf[mi][ks], a0, 0, 0, 0);
            a1 = __builtin_amdgcn_mfma_f32_16x16x32_f16(s.kf[1][ks], qf[mi][ks], a1, 0, 0, 0);
        }
        half8 pf;
#pragma unroll
        for (int j = 0; j < 4; ++j) {
            pf[j]     = (_Float16)exp2_fast(a0[j]);
            pf[j + 4] = (_Float16)exp2_fast(a1[j]);
        }
        lacc[mi] = __builtin_amdgcn_mfma_f32_16x16x32_f16(ones, pf, lacc[mi], 0, 0, 0);
#pragma unroll
        for (int di = 0; di < 4; ++di)
            oacc[mi][di] = __builtin_amdgcn_mfma_f32_16x16x32_f16(s.vf[di], pf, oacc[mi][di], 0, 0, 0);
    }
}

__global__ __launch_bounds__(128, 2) void attn(const _Float16* __restrict__ qg,
                                               const _Float16* __restrict__ kg,
                                               const _Float16* __restrict__ vtg,
                                               _Float16* __restrict__ o) {
    int bphys = blockIdx.x;                          // 0..1535
    int jj = (bphys & 7) * 192 + (bphys >> 3);       // XCD swizzle: head stays on one XCD
    int bh = jj >> 3, qt = jj & 7;
    int b = bh / H_, h = bh % H_;
    int tid = threadIdx.x;
    int wid = tid >> 6, lane = tid & 63;
    int lg = lane >> 4, l15 = lane & 15;
    size_t base = (size_t)bh << 10;
    int qw0 = qt * 128 + wid * 64;                   // this wave's 64 q-rows

    const _Float16* qrow = qg + (base + qw0 + l15) * 64 + lg * 8;
    half8 qf[4][2];
#pragma unroll
    for (int mi = 0; mi < 4; ++mi)
#pragma unroll
        for (int ks = 0; ks < 2; ++ks)
            qf[mi][ks] = *(const half8*)(qrow + mi * 1024 + ks * 32);

    const _Float16* kp = kg + (size_t)bh * 65536 + lane * 8;
    const _Float16* vp = vtg + (size_t)bh * 65536 + lane * 8;

    half8 ones;
#pragma unroll
    for (int i = 0; i < 8; ++i) ones[i] = (_Float16)1.0f;

    f32x4 oacc[4][4] = {};
    f32x4 lacc[4] = {};

    KV s0, s1;
    ldKV(s0, kp, vp, 0);
    for (int t = 0; t < 16; ++t) {
        ldKV(s1, kp, vp, (2 * t + 1) & 31);
        blockKV(s0, qf, oacc, lacc, ones);
        ldKV(s0, kp, vp, (2 * t + 2) & 31);          // wraps harmlessly on last iter
        blockKV(s1, qf, oacc, lacc, ones);
    }

#pragma unroll
    for (int mi = 0; mi < 4; ++mi) {
        float inv = 1.f / lacc[mi][0];
        int q = qw0 + mi * 16 + l15;
        size_t rowb = ((size_t)(b * N_ + q)) * D_ + h * 64 + lg * 4;
#pragma unroll
        for (int di = 0; di < 4; ++di) {
            half4 h4;
#pragma unroll
            for (int j = 0; j < 4; ++j) h4[j] = (_Float16)(oacc[mi][di][j] * inv);
            *(half4*)&o[rowb + di * 16] = h4;
        }
    }
}

// ---------------- proj GEMM: ao[16384][768] @ WprojT^T + b -> out f32 ----------------
__global__ __launch_bounds__(256) void gemm_proj(const _Float16* __restrict__ A,
                                                 const _Float16* __restrict__ BT,
                                                 const float* __restrict__ bias,
                                                 float* __restrict__ out) {
    __shared__ _Float16 As[3][128 * 32];
    __shared__ _Float16 Bs[3][128 * 32];
    const int K = D_;
    int xcd = blockIdx.x & 7, loc = blockIdx.x >> 3;     // 768 = 8 XCD * (16 m * 6 n)
    int m0 = (xcd * 16 + loc / 6) * 128;
    int n0 = (loc % 6) * 128;
    int tid = threadIdx.x;
    int wave = tid >> 6, lane = tid & 63;
    int wm = wave >> 1, wn = wave & 1;
    int lg = lane >> 4, l15 = lane & 15;
    int xorr = (l15 >> 1) & 3;

    auto stage = [&](int buf, int tstep) {
        int k0 = tstep * 32;
#pragma unroll
        for (int i = 0; i < 2; ++i) {
            int cb = (i * 4 + wave) * 64;
            int chunk = cb + lane;
            int r = chunk >> 2, c = chunk & 3;
            int cg = c ^ ((r >> 1) & 3);
            gl16(&A[(size_t)(m0 + r) * K + k0 + cg * 8], &As[buf][cb * 8]);
            gl16(&BT[(size_t)(n0 + r) * K + k0 + cg * 8], &Bs[buf][cb * 8]);
        }
    };

    f32x4 acc[4][4] = {};
    stage(0, 0); stage(1, 1); stage(2, 2);
    for (int t = 0; t < 24; ++t) {
        int cur = t % 3;
        asm volatile("s_waitcnt vmcnt(8)" ::: "memory");
        __builtin_amdgcn_s_barrier();
        const _Float16* asb = As[cur];
        const _Float16* bsb = Bs[cur];
        half8 af[4], bf[4];
#pragma unroll
        for (int i = 0; i < 4; ++i) {
            af[i] = *(const half8*)&asb[(wm * 64 + i * 16 + l15) * 32 + (lg ^ xorr) * 8];
            bf[i] = *(const half8*)&bsb[(wn * 64 + i * 16 + l15) * 32 + (lg ^ xorr) * 8];
        }
#pragma unroll
        for (int mi = 0; mi < 4; ++mi)
#pragma unroll
            for (int ni = 0; ni < 4; ++ni)
                acc[mi][ni] = __builtin_amdgcn_mfma_f32_16x16x32_f16(af[mi], bf[ni], acc[mi][ni], 0, 0, 0);
        __builtin_amdgcn_sched_barrier(0);
        __builtin_amdgcn_s_barrier();
        stage(cur, (t + 3) % 24);
    }
#pragma unroll
    for (int mi = 0; mi < 4; ++mi)
#pragma unroll
        for (int ni = 0; ni < 4; ++ni) {
            int col = n0 + wn * 64 + ni * 16 + l15;
            float bv = bias[col];
#pragma unroll
            for (int j = 0; j < 4; ++j) {
                int row = m0 + wm * 64 + mi * 16 + lg * 4 + j;
                out[(size_t)row * D_ + col] = acc[mi][ni][j] + bv;
            }
        }
}

// ---------------- launch ----------------
extern "C" void kernel_launch(void* const* d_in, const int* in_sizes, int n_in,
                              void* d_out, int out_size, void* d_ws, size_t ws_size,
                              hipStream_t stream) {
    const float* x      = (const float*)d_in[0];
    const float* ln_g   = (const float*)d_in[1];
    const float* ln_b   = (const float*)d_in[2];
    const float* W_qkv  = (const float*)d_in[3];
    const float* b_qkv  = (const float*)d_in[4];
    const float* qn_g   = (const float*)d_in[5];
    const float* qn_b   = (const float*)d_in[6];
    const float* kn_g   = (const float*)d_in[7];
    const float* kn_b   = (const float*)d_in[8];
    const float* W_proj = (const float*)d_in[9];
    const float* b_proj = (const float*)d_in[10];
    float* out = (float*)d_out;
    char* ws = (char*)d_ws;

    constexpr size_t XN_SZ    = (size_t)M_ * D_ * 2;
    constexpr size_t WQKVT_SZ = (size_t)QKVN_ * D_ * 2;
    constexpr size_t WPROJT_SZ= (size_t)D_ * D_ * 2;
    constexpr size_t HEAD_SZ  = (size_t)B_ * H_ * N_ * 64 * 2;

    _Float16* xn     = (_Float16*)(ws);
    _Float16* wqkvT  = (_Float16*)(ws + XN_SZ);
    _Float16* wprojT = (_Float16*)(ws + XN_SZ + WQKVT_SZ);
    _Float16* qb     = (_Float16*)(ws + XN_SZ + WQKVT_SZ + WPROJT_SZ);
    _Float16* kb     = (_Float16*)((char*)qb + HEAD_SZ);   // K fragment-major
    _Float16* vtb    = (_Float16*)((char*)kb + HEAD_SZ);   // V fragment-major
    _Float16* ao     = xn;   // xn dead after gemm_qkv

    convert_w<<<576, 256, 0, stream>>>(W_qkv, W_proj, wqkvT, wprojT);
    ln_embed<<<M_, 256, 0, stream>>>(x, ln_g, ln_b, xn);
    gemm_qkv<<<M_ / 128 * (QKVN_ / 128), 256, 0, stream>>>(xn, wqkvT, b_qkv,
                                                           qn_g, qn_b, kn_g, kn_b,
                                                           qb, kb, vtb);
    attn<<<B_ * H_ * (N_ / 128), 128, 0, stream>>>(qb, kb, vtb, ao);
    gemm_proj<<<M_ / 128 * (D_ / 128), 256, 0, stream>>>(ao, wprojT, b_proj, out);
}

// Round 7
// 203.130 us; speedup vs baseline: 1.1529x; 1.1529x over previous
//
#include <hip/hip_runtime.h>

typedef _Float16 half8 __attribute__((ext_vector_type(8)));
typedef _Float16 half4 __attribute__((ext_vector_type(4)));
typedef _Float16 half2v __attribute__((ext_vector_type(2)));
typedef float f32x4 __attribute__((ext_vector_type(4)));

#define B_    16
#define N_    1024
#define D_    768
#define H_    12
#define M_    (B_ * N_)     // 16384
#define QKVN_ 2304
#define EPS_  1e-5f
#define QS_   0.18033688011112042f   // 0.125 * log2(e)

__device__ __forceinline__ float exp2_fast(float x) {
#if __has_builtin(__builtin_amdgcn_exp2f)
    return __builtin_amdgcn_exp2f(x);
#else
    return __builtin_exp2f(x);
#endif
}

// fragment-pack offset (halves): [t16][kc=24][lg=4][p=16][e=8]
// packed[t16][kc][lg][p][e] = ROWMAJOR[t16*16 + p][kc*32 + lg*8 + e]
__device__ __forceinline__ size_t pk(int t16, int kc, int lg, int p, int e) {
    return ((size_t)(t16 * 24 + kc) * 4 + lg) * 128 + p * 8 + e;
}

// ---------------- weight cast + fragment-major pack ----------------
__global__ __launch_bounds__(256) void convert_w(const float* __restrict__ Wqkv,
                                                 const float* __restrict__ Wproj,
                                                 _Float16* __restrict__ wqkv_p,
                                                 _Float16* __restrict__ wproj_p) {
    int idx = blockIdx.x * 256 + threadIdx.x;
    const int n1 = D_ * QKVN_;                 // 1769472
    int k, n; float v; _Float16* dst;
    if (idx < n1) { k = idx / QKVN_; n = idx % QKVN_; v = Wqkv[idx]; dst = wqkv_p; }
    else { int r = idx - n1; k = r / D_; n = r % D_; v = Wproj[r]; dst = wproj_p; }
    dst[pk(n >> 4, k >> 5, (k >> 3) & 3, n & 15, k & 7)] = (_Float16)v;
}

// ---------------- embed LayerNorm -> xn packed A-fragment-major ----------------
__global__ __launch_bounds__(256) void ln_embed(const float* __restrict__ x,
                                                const float* __restrict__ g,
                                                const float* __restrict__ bb,
                                                _Float16* __restrict__ xp) {
    int row = blockIdx.x;
    int tid = threadIdx.x;
    const float2* xr = (const float2*)(x + (size_t)row * D_);   // 384 float2
    float2 v0 = xr[tid];
    float2 v1 = make_float2(0.f, 0.f);
    if (tid < 128) v1 = xr[256 + tid];
    float s = v0.x + v0.y + v1.x + v1.y;
    float q = v0.x * v0.x + v0.y * v0.y + v1.x * v1.x + v1.y * v1.y;
#pragma unroll
    for (int m = 32; m >= 1; m >>= 1) {
        s += __shfl_xor(s, m);
        q += __shfl_xor(q, m);
    }
    __shared__ float ss[4], qq[4];
    int wave = tid >> 6;
    if ((tid & 63) == 0) { ss[wave] = s; qq[wave] = q; }
    __syncthreads();
    float S = ss[0] + ss[1] + ss[2] + ss[3];
    float Q = qq[0] + qq[1] + qq[2] + qq[3];
    float mean = S * (1.f / 768.f);
    float var  = Q * (1.f / 768.f) - mean * mean;
    float rstd = rsqrtf(var + EPS_);
    const float2* g2 = (const float2*)g;
    const float2* b2 = (const float2*)bb;
    int mt = row >> 4, p = row & 15;
    {
        int d0 = 2 * tid;
        float2 ga = g2[tid], ba = b2[tid];
        half2v w;
        w[0] = (_Float16)((v0.x - mean) * rstd * ga.x + ba.x);
        w[1] = (_Float16)((v0.y - mean) * rstd * ga.y + ba.y);
        *(half2v*)&xp[pk(mt, d0 >> 5, (d0 >> 3) & 3, p, d0 & 7)] = w;
    }
    if (tid < 128) {
        int d0 = 512 + 2 * tid;
        float2 ga = g2[256 + tid], ba = b2[256 + tid];
        half2v w;
        w[0] = (_Float16)((v1.x - mean) * rstd * ga.x + ba.x);
        w[1] = (_Float16)((v1.y - mean) * rstd * ga.y + ba.y);
        *(half2v*)&xp[pk(mt, d0 >> 5, (d0 >> 3) & 3, p, d0 & 7)] = w;
    }
}

// ---------------- QKV GEMM: pure-register, zero LDS/barriers ----------------
// A,B pre-packed fragment-major: per K-step 8 coalesced 1KB loads + 16 MFMA.
__global__ __launch_bounds__(256, 3) void gemm_qkv(const _Float16* __restrict__ Ap,
                                                   const _Float16* __restrict__ Bp,
                                                   const float* __restrict__ bias,
                                                   const float* __restrict__ qn_g,
                                                   const float* __restrict__ qn_b,
                                                   const float* __restrict__ kn_g,
                                                   const float* __restrict__ kn_b,
                                                   _Float16* __restrict__ qo,
                                                   _Float16* __restrict__ ko,
                                                   _Float16* __restrict__ vt) {
    int xcd = blockIdx.x & 7, loc = blockIdx.x >> 3;     // 2304 = 8 * (16 m * 18 n)
    int mt0 = (xcd * 16 + loc / 18) * 8;                 // m-tile16 base
    int nt0 = (loc % 18) * 8;
    int tid = threadIdx.x;
    int wave = tid >> 6, lane = tid & 63;
    int wm = wave >> 1, wn = wave & 1;
    int lg = lane >> 4, l15 = lane & 15;

    const _Float16* pa[4];
    const _Float16* pb[4];
#pragma unroll
    for (int i = 0; i < 4; ++i) {
        pa[i] = Ap + (size_t)(mt0 + wm * 4 + i) * 12288 + lane * 8;
        pb[i] = Bp + (size_t)(nt0 + wn * 4 + i) * 12288 + lane * 8;
    }
    f32x4 acc[4][4] = {};
    half8 a0[4], b0[4], a1[4], b1[4];
    auto ld = [&](half8 (&a)[4], half8 (&b)[4], int t) {
        int off = t * 512;
#pragma unroll
        for (int i = 0; i < 4; ++i) {
            a[i] = *(const half8*)(pa[i] + off);
            b[i] = *(const half8*)(pb[i] + off);
        }
    };
    auto mm = [&](half8 (&a)[4], half8 (&b)[4]) {
#pragma unroll
        for (int mi = 0; mi < 4; ++mi)
#pragma unroll
            for (int ni = 0; ni < 4; ++ni)
                acc[mi][ni] = __builtin_amdgcn_mfma_f32_16x16x32_f16(a[mi], b[ni], acc[mi][ni], 0, 0, 0);
    };
    ld(a0, b0, 0);
    for (int tt = 0; tt < 11; ++tt) {
        ld(a1, b1, 2 * tt + 1);
        mm(a0, b0);
        ld(a0, b0, 2 * tt + 2);
        mm(a1, b1);
    }
    ld(a1, b1, 23);
    mm(a0, b0);
    mm(a1, b1);

    // ---- epilogue: fused per-head LN + fragment-major scatter (unchanged logic) ----
    int m0 = mt0 * 16, n0 = nt0 * 16;
    int col0 = n0 + wn * 64;
    int s = col0 / 768;
    int hcol = (col0 % 768) >> 6;
    float qkvb[4];
#pragma unroll
    for (int ni = 0; ni < 4; ++ni) qkvb[ni] = bias[col0 + ni * 16 + l15];

    if (s == 2) {
#pragma unroll
        for (int mi = 0; mi < 4; ++mi) {
            int r0 = m0 + wm * 64 + mi * 16 + lg * 4;
            int bidx = r0 >> 10, pos = r0 & 1023;
            int kvblk = pos >> 5, h = (pos >> 4) & 1, lgR = (pos >> 2) & 3;
            size_t vbase = ((size_t)(bidx * H_ + hcol) * 32 + kvblk) * 4;
#pragma unroll
            for (int ni = 0; ni < 4; ++ni) {
                half4 h4;
#pragma unroll
                for (int j = 0; j < 4; ++j) h4[j] = (_Float16)(acc[mi][ni][j] + qkvb[ni]);
                *(half4*)&vt[(vbase + ni) * 512 + lgR * 128 + l15 * 8 + h * 4] = h4;
            }
        }
    } else {
        const float* gg = (s == 0) ? qn_g : kn_g;
        const float* bb = (s == 0) ? qn_b : kn_b;
        float gv[4], bv[4];
#pragma unroll
        for (int ni = 0; ni < 4; ++ni) { gv[ni] = gg[ni * 16 + l15]; bv[ni] = bb[ni * 16 + l15]; }
#pragma unroll
        for (int mi = 0; mi < 4; ++mi) {
#pragma unroll
            for (int j = 0; j < 4; ++j) {
                float v[4];
                float sm = 0.f, sq = 0.f;
#pragma unroll
                for (int ni = 0; ni < 4; ++ni) {
                    v[ni] = acc[mi][ni][j] + qkvb[ni];
                    sm += v[ni];
                    sq += v[ni] * v[ni];
                }
#pragma unroll
                for (int msk = 1; msk < 16; msk <<= 1) {
                    sm += __shfl_xor(sm, msk);
                    sq += __shfl_xor(sq, msk);
                }
                float mean = sm * (1.f / 64.f);
                float var  = sq * (1.f / 64.f) - mean * mean;
                float rstd = rsqrtf(var + EPS_);
                int row = m0 + wm * 64 + mi * 16 + lg * 4 + j;
                int bidx = row >> 10, pos = row & 1023;
                if (s == 0) {
                    size_t rbase = ((size_t)(bidx * H_ + hcol) * 1024 + pos) * 64;
#pragma unroll
                    for (int ni = 0; ni < 4; ++ni) {
                        float o = (v[ni] - mean) * rstd * gv[ni] + bv[ni];
                        qo[rbase + ni * 16 + l15] = (_Float16)(o * QS_);
                    }
                } else {
                    int kvblk = pos >> 5, nh = (pos >> 4) & 1, l15R = pos & 15;
                    size_t base2 = ((size_t)(bidx * H_ + hcol) * 32 + kvblk) * 4 + nh * 2;
#pragma unroll
                    for (int ni = 0; ni < 4; ++ni) {
                        float o = (v[ni] - mean) * rstd * gv[ni] + bv[ni];
                        int ks = ni >> 1, lgR = ((ni & 1) << 1) | (l15 >> 3), elem = l15 & 7;
                        ko[(base2 + ks) * 512 + lgR * 128 + l15R * 8 + elem] = (_Float16)o;
                    }
                }
            }
        }
    }
}

// ---------------- flash attention: pure-register; output packed for proj-A ----------
struct KV {
    half8 kf[2][2];   // [nh][ks]
    half8 vf[4];      // [di]
};

__device__ __forceinline__ void ldKV(KV& s, const _Float16* kp, const _Float16* vp, int kvblk) {
    const _Float16* kb = kp + (size_t)kvblk * 2048;
#pragma unroll
    for (int nh = 0; nh < 2; ++nh)
#pragma unroll
        for (int ks = 0; ks < 2; ++ks)
            s.kf[nh][ks] = *(const half8*)(kb + (nh * 2 + ks) * 512);
    const _Float16* vb = vp + (size_t)kvblk * 2048;
#pragma unroll
    for (int di = 0; di < 4; ++di)
        s.vf[di] = *(const half8*)(vb + di * 512);
}

__device__ __forceinline__ void blockKV(const KV& s, const half8 (&qf)[4][2],
                                        f32x4 (&oacc)[4][4], f32x4 (&lacc)[4],
                                        half8 ones) {
#pragma unroll
    for (int mi = 0; mi < 4; ++mi) {
        f32x4 a0 = {}, a1 = {};
#pragma unroll
        for (int ks = 0; ks < 2; ++ks) {
            a0 = __builtin_amdgcn_mfma_f32_16x16x32_f16(s.kf[0][ks], qf[mi][ks], a0, 0, 0, 0);
            a1 = __builtin_amdgcn_mfma_f32_16x16x32_f16(s.kf[1][ks], qf[mi][ks], a1, 0, 0, 0);
        }
        half8 pf;
#pragma unroll
        for (int j = 0; j < 4; ++j) {
            pf[j]     = (_Float16)exp2_fast(a0[j]);
            pf[j + 4] = (_Float16)exp2_fast(a1[j]);
        }
        lacc[mi] = __builtin_amdgcn_mfma_f32_16x16x32_f16(ones, pf, lacc[mi], 0, 0, 0);
#pragma unroll
        for (int di = 0; di < 4; ++di)
            oacc[mi][di] = __builtin_amdgcn_mfma_f32_16x16x32_f16(s.vf[di], pf, oacc[mi][di], 0, 0, 0);
    }
}

__global__ __launch_bounds__(128, 2) void attn(const _Float16* __restrict__ qg,
                                               const _Float16* __restrict__ kg,
                                               const _Float16* __restrict__ vtg,
                                               _Float16* __restrict__ op) {
    int bphys = blockIdx.x;                          // 0..1535
    int jj = (bphys & 7) * 192 + (bphys >> 3);       // XCD swizzle
    int bh = jj >> 3, qt = jj & 7;
    int b = bh / H_, h = bh % H_;
    int tid = threadIdx.x;
    int wid = tid >> 6, lane = tid & 63;
    int lg = lane >> 4, l15 = lane & 15;
    size_t base = (size_t)bh << 10;
    int qw0 = qt * 128 + wid * 64;

    const _Float16* qrow = qg + (base + qw0 + l15) * 64 + lg * 8;
    half8 qf[4][2];
#pragma unroll
    for (int mi = 0; mi < 4; ++mi)
#pragma unroll
        for (int ks = 0; ks < 2; ++ks)
            qf[mi][ks] = *(const half8*)(qrow + mi * 1024 + ks * 32);

    const _Float16* kp = kg + (size_t)bh * 65536 + lane * 8;
    const _Float16* vp = vtg + (size_t)bh * 65536 + lane * 8;

    half8 ones;
#pragma unroll
    for (int i = 0; i < 8; ++i) ones[i] = (_Float16)1.0f;

    f32x4 oacc[4][4] = {};
    f32x4 lacc[4] = {};

    KV s0, s1;
    ldKV(s0, kp, vp, 0);
    for (int t = 0; t < 16; ++t) {
        ldKV(s1, kp, vp, (2 * t + 1) & 31);
        blockKV(s0, qf, oacc, lacc, ones);
        ldKV(s0, kp, vp, (2 * t + 2) & 31);
        blockKV(s1, qf, oacc, lacc, ones);
    }

    // write O packed as gemm_proj A-fragments: k = 64h + di*16 + lg*4 + j
#pragma unroll
    for (int mi = 0; mi < 4; ++mi) {
        float inv = 1.f / lacc[mi][0];
        int mt = b * 64 + (qw0 >> 4) + mi;
#pragma unroll
        for (int di = 0; di < 4; ++di) {
            half4 h4;
#pragma unroll
            for (int j = 0; j < 4; ++j) h4[j] = (_Float16)(oacc[mi][di][j] * inv);
            *(half4*)&op[pk(mt, 2 * h + (di >> 1), (di & 1) * 2 + (lg >> 1), l15, (lg & 1) * 4)] = h4;
        }
    }
}

// ---------------- proj GEMM: pure-register, zero LDS/barriers ----------------
__global__ __launch_bounds__(256, 3) void gemm_proj(const _Float16* __restrict__ Ap,
                                                    const _Float16* __restrict__ Bp,
                                                    const float* __restrict__ bias,
                                                    float* __restrict__ out) {
    int xcd = blockIdx.x & 7, loc = blockIdx.x >> 3;     // 768 = 8 * (16 m * 6 n)
    int mt0 = (xcd * 16 + loc / 6) * 8;
    int nt0 = (loc % 6) * 8;
    int tid = threadIdx.x;
    int wave = tid >> 6, lane = tid & 63;
    int wm = wave >> 1, wn = wave & 1;
    int lg = lane >> 4, l15 = lane & 15;

    const _Float16* pa[4];
    const _Float16* pb[4];
#pragma unroll
    for (int i = 0; i < 4; ++i) {
        pa[i] = Ap + (size_t)(mt0 + wm * 4 + i) * 12288 + lane * 8;
        pb[i] = Bp + (size_t)(nt0 + wn * 4 + i) * 12288 + lane * 8;
    }
    f32x4 acc[4][4] = {};
    half8 a0[4], b0[4], a1[4], b1[4];
    auto ld = [&](half8 (&a)[4], half8 (&b)[4], int t) {
        int off = t * 512;
#pragma unroll
        for (int i = 0; i < 4; ++i) {
            a[i] = *(const half8*)(pa[i] + off);
            b[i] = *(const half8*)(pb[i] + off);
        }
    };
    auto mm = [&](half8 (&a)[4], half8 (&b)[4]) {
#pragma unroll
        for (int mi = 0; mi < 4; ++mi)
#pragma unroll
            for (int ni = 0; ni < 4; ++ni)
                acc[mi][ni] = __builtin_amdgcn_mfma_f32_16x16x32_f16(a[mi], b[ni], acc[mi][ni], 0, 0, 0);
    };
    ld(a0, b0, 0);
    for (int tt = 0; tt < 11; ++tt) {
        ld(a1, b1, 2 * tt + 1);
        mm(a0, b0);
        ld(a0, b0, 2 * tt + 2);
        mm(a1, b1);
    }
    ld(a1, b1, 23);
    mm(a0, b0);
    mm(a1, b1);

    int m0 = mt0 * 16, n0 = nt0 * 16;
#pragma unroll
    for (int mi = 0; mi < 4; ++mi)
#pragma unroll
        for (int ni = 0; ni < 4; ++ni) {
            int col = n0 + wn * 64 + ni * 16 + l15;
            float bv = bias[col];
#pragma unroll
            for (int j = 0; j < 4; ++j) {
                int row = m0 + wm * 64 + mi * 16 + lg * 4 + j;
                out[(size_t)row * D_ + col] = acc[mi][ni][j] + bv;
            }
        }
}

// ---------------- launch ----------------
extern "C" void kernel_launch(void* const* d_in, const int* in_sizes, int n_in,
                              void* d_out, int out_size, void* d_ws, size_t ws_size,
                              hipStream_t stream) {
    const float* x      = (const float*)d_in[0];
    const float* ln_g   = (const float*)d_in[1];
    const float* ln_b   = (const float*)d_in[2];
    const float* W_qkv  = (const float*)d_in[3];
    const float* b_qkv  = (const float*)d_in[4];
    const float* qn_g   = (const float*)d_in[5];
    const float* qn_b   = (const float*)d_in[6];
    const float* kn_g   = (const float*)d_in[7];
    const float* kn_b   = (const float*)d_in[8];
    const float* W_proj = (const float*)d_in[9];
    const float* b_proj = (const float*)d_in[10];
    float* out = (float*)d_out;
    char* ws = (char*)d_ws;

    constexpr size_t XN_SZ    = (size_t)M_ * D_ * 2;
    constexpr size_t WQKVT_SZ = (size_t)QKVN_ * D_ * 2;
    constexpr size_t WPROJT_SZ= (size_t)D_ * D_ * 2;
    constexpr size_t HEAD_SZ  = (size_t)B_ * H_ * N_ * 64 * 2;

    _Float16* xn_p   = (_Float16*)(ws);                      // A-frag-packed LN(x); reused as ao_p
    _Float16* wqkv_p = (_Float16*)(ws + XN_SZ);
    _Float16* wproj_p= (_Float16*)(ws + XN_SZ + WQKVT_SZ);
    _Float16* qb     = (_Float16*)(ws + XN_SZ + WQKVT_SZ + WPROJT_SZ);
    _Float16* kb     = (_Float16*)((char*)qb + HEAD_SZ);     // K fragment-major
    _Float16* vtb    = (_Float16*)((char*)kb + HEAD_SZ);     // V fragment-major
    _Float16* ao_p   = xn_p;                                 // xn dead after gemm_qkv

    convert_w<<<9216, 256, 0, stream>>>(W_qkv, W_proj, wqkv_p, wproj_p);
    ln_embed<<<M_, 256, 0, stream>>>(x, ln_g, ln_b, xn_p);
    gemm_qkv<<<M_ / 128 * (QKVN_ / 128), 256, 0, stream>>>(xn_p, wqkv_p, b_qkv,
                                                           qn_g, qn_b, kn_g, kn_b,
                                                           qb, kb, vtb);
    attn<<<B_ * H_ * (N_ / 128), 128, 0, stream>>>(qb, kb, vtb, ao_p);
    gemm_proj<<<M_ / 128 * (D_ / 128), 256, 0, stream>>>(ao_p, wproj_p, b_proj, out);
}

// Round 8
// 201.620 us; speedup vs baseline: 1.1616x; 1.0075x over previous
//
#include <hip/hip_runtime.h>

typedef _Float16 half8 __attribute__((ext_vector_type(8)));
typedef _Float16 half4 __attribute__((ext_vector_type(4)));
typedef _Float16 half2v __attribute__((ext_vector_type(2)));
typedef float f32x4 __attribute__((ext_vector_type(4)));

#define B_    16
#define N_    1024
#define D_    768
#define H_    12
#define M_    (B_ * N_)     // 16384
#define QKVN_ 2304
#define EPS_  1e-5f
#define QS_   0.18033688011112042f   // 0.125 * log2(e)

__device__ __forceinline__ float exp2_fast(float x) {
#if __has_builtin(__builtin_amdgcn_exp2f)
    return __builtin_amdgcn_exp2f(x);
#else
    return __builtin_exp2f(x);
#endif
}

// fragment-pack offset (halves): [t16][kc=24][lg=4][p=16][e=8]
// packed[t16][kc][lg][p][e] = ROWMAJOR[t16*16 + p][kc*32 + lg*8 + e]
__device__ __forceinline__ size_t pk(int t16, int kc, int lg, int p, int e) {
    return ((size_t)(t16 * 24 + kc) * 4 + lg) * 128 + p * 8 + e;
}

// ---------------- weight cast + fragment pack (LDS-tiled, coalesced both sides) ----------
__global__ __launch_bounds__(256) void convert_w(const float* __restrict__ Wqkv,
                                                 const float* __restrict__ Wproj,
                                                 _Float16* __restrict__ wqkv_p,
                                                 _Float16* __restrict__ wproj_p) {
    __shared__ float T[64][65];                 // T[n_local][k_local], pad-65: conflict-free
    int t = blockIdx.x;
    const float* W; _Float16* O; int NW, k0, n0;
    if (t < 432) { W = Wqkv;  O = wqkv_p;  NW = QKVN_; k0 = (t % 12) * 64; n0 = (t / 12) * 64; }
    else { t -= 432; W = Wproj; O = wproj_p; NW = D_;  k0 = (t % 12) * 64; n0 = (t / 12) * 64; }
    int c = threadIdx.x & 63, r4 = threadIdx.x >> 6;
#pragma unroll
    for (int i = 0; i < 16; ++i) {
        int k = i * 4 + r4;
        T[c][k] = W[(size_t)(k0 + k) * NW + n0 + c];   // coalesced read, 2-way LDS write
    }
    __syncthreads();
    int g = threadIdx.x >> 5, s2 = threadIdx.x & 31;   // 8 output granules of 512 halves
    int ntl = g & 3, kcl = g >> 2;
    int nt = (n0 >> 4) + ntl, kc = (k0 >> 5) + kcl;
#pragma unroll
    for (int hh = 0; hh < 2; ++hh) {
        int s = s2 + hh * 32;
        int lg = s >> 4, p = s & 15;
        half8 v;
#pragma unroll
        for (int e = 0; e < 8; ++e)
            v[e] = (_Float16)T[ntl * 16 + p][kcl * 32 + lg * 8 + e];
        *(half8*)&O[((size_t)(nt * 24 + kc) * 4 + lg) * 128 + p * 8] = v;
    }
}

// ---------------- embed LayerNorm -> xn packed A-fragment-major ----------------
__global__ __launch_bounds__(256) void ln_embed(const float* __restrict__ x,
                                                const float* __restrict__ g,
                                                const float* __restrict__ bb,
                                                _Float16* __restrict__ xp) {
    int row = blockIdx.x;
    int tid = threadIdx.x;
    const float2* xr = (const float2*)(x + (size_t)row * D_);   // 384 float2
    float2 v0 = xr[tid];
    float2 v1 = make_float2(0.f, 0.f);
    if (tid < 128) v1 = xr[256 + tid];
    float s = v0.x + v0.y + v1.x + v1.y;
    float q = v0.x * v0.x + v0.y * v0.y + v1.x * v1.x + v1.y * v1.y;
#pragma unroll
    for (int m = 32; m >= 1; m >>= 1) {
        s += __shfl_xor(s, m);
        q += __shfl_xor(q, m);
    }
    __shared__ float ss[4], qq[4];
    int wave = tid >> 6;
    if ((tid & 63) == 0) { ss[wave] = s; qq[wave] = q; }
    __syncthreads();
    float S = ss[0] + ss[1] + ss[2] + ss[3];
    float Q = qq[0] + qq[1] + qq[2] + qq[3];
    float mean = S * (1.f / 768.f);
    float var  = Q * (1.f / 768.f) - mean * mean;
    float rstd = rsqrtf(var + EPS_);
    const float2* g2 = (const float2*)g;
    const float2* b2 = (const float2*)bb;
    int mt = row >> 4, p = row & 15;
    {
        int d0 = 2 * tid;
        float2 ga = g2[tid], ba = b2[tid];
        half2v w;
        w[0] = (_Float16)((v0.x - mean) * rstd * ga.x + ba.x);
        w[1] = (_Float16)((v0.y - mean) * rstd * ga.y + ba.y);
        *(half2v*)&xp[pk(mt, d0 >> 5, (d0 >> 3) & 3, p, d0 & 7)] = w;
    }
    if (tid < 128) {
        int d0 = 512 + 2 * tid;
        float2 ga = g2[256 + tid], ba = b2[256 + tid];
        half2v w;
        w[0] = (_Float16)((v1.x - mean) * rstd * ga.x + ba.x);
        w[1] = (_Float16)((v1.y - mean) * rstd * ga.y + ba.y);
        *(half2v*)&xp[pk(mt, d0 >> 5, (d0 >> 3) & 3, p, d0 & 7)] = w;
    }
}

// ---------------- QKV GEMM: pure-register, depth-2 prefetch, L2-resident A panel ----------
// Block order: XCD-local, m FASTEST (n outer) -> per-XCD working set = A-panel
// 3.1MB (L2-resident) + one streaming 196KB B block. All loads ~L2-hit.
__global__ __launch_bounds__(256, 3) void gemm_qkv(const _Float16* __restrict__ Ap,
                                                   const _Float16* __restrict__ Bp,
                                                   const float* __restrict__ bias,
                                                   const float* __restrict__ qn_g,
                                                   const float* __restrict__ qn_b,
                                                   const float* __restrict__ kn_g,
                                                   const float* __restrict__ kn_b,
                                                   _Float16* __restrict__ qo,
                                                   _Float16* __restrict__ ko,
                                                   _Float16* __restrict__ vt) {
    int xcd = blockIdx.x & 7, loc = blockIdx.x >> 3;     // 2304 = 8 * (16 m * 18 n)
    int mt0 = (xcd * 16 + (loc & 15)) * 8;               // m fastest within XCD
    int nt0 = (loc >> 4) * 8;
    int tid = threadIdx.x;
    int wave = tid >> 6, lane = tid & 63;
    int wm = wave >> 1, wn = wave & 1;
    int lg = lane >> 4, l15 = lane & 15;

    const _Float16* pa[4];
    const _Float16* pb[4];
#pragma unroll
    for (int i = 0; i < 4; ++i) {
        pa[i] = Ap + (size_t)(mt0 + wm * 4 + i) * 12288 + lane * 8;
        pb[i] = Bp + (size_t)(nt0 + wn * 4 + i) * 12288 + lane * 8;
    }
    f32x4 acc[4][4] = {};
    half8 a0[4], b0[4], a1[4], b1[4], a2[4], b2[4];
    auto ld = [&](half8 (&a)[4], half8 (&b)[4], int t) {
        int off = t * 512;
#pragma unroll
        for (int i = 0; i < 4; ++i) {
            a[i] = *(const half8*)(pa[i] + off);
            b[i] = *(const half8*)(pb[i] + off);
        }
    };
    auto mm = [&](half8 (&a)[4], half8 (&b)[4]) {
#pragma unroll
        for (int mi = 0; mi < 4; ++mi)
#pragma unroll
            for (int ni = 0; ni < 4; ++ni)
                acc[mi][ni] = __builtin_amdgcn_mfma_f32_16x16x32_f16(a[mi], b[ni], acc[mi][ni], 0, 0, 0);
    };
    // depth-2 rotation over 3 named sets (static indexing only)
    ld(a0, b0, 0); ld(a1, b1, 1);
    for (int tt = 0; tt < 8; ++tt) {
        ld(a2, b2, 3 * tt + 2);
        mm(a0, b0);
        if (tt < 7) ld(a0, b0, 3 * tt + 3);
        mm(a1, b1);
        if (tt < 7) ld(a1, b1, 3 * tt + 4);
        mm(a2, b2);
    }

    // ---- epilogue: fused per-head LN + fragment-major scatter ----
    int m0 = mt0 * 16, n0 = nt0 * 16;
    int col0 = n0 + wn * 64;
    int s = col0 / 768;
    int hcol = (col0 % 768) >> 6;
    float qkvb[4];
#pragma unroll
    for (int ni = 0; ni < 4; ++ni) qkvb[ni] = bias[col0 + ni * 16 + l15];

    if (s == 2) {
#pragma unroll
        for (int mi = 0; mi < 4; ++mi) {
            int r0 = m0 + wm * 64 + mi * 16 + lg * 4;
            int bidx = r0 >> 10, pos = r0 & 1023;
            int kvblk = pos >> 5, h = (pos >> 4) & 1, lgR = (pos >> 2) & 3;
            size_t vbase = ((size_t)(bidx * H_ + hcol) * 32 + kvblk) * 4;
#pragma unroll
            for (int ni = 0; ni < 4; ++ni) {
                half4 h4;
#pragma unroll
                for (int j = 0; j < 4; ++j) h4[j] = (_Float16)(acc[mi][ni][j] + qkvb[ni]);
                *(half4*)&vt[(vbase + ni) * 512 + lgR * 128 + l15 * 8 + h * 4] = h4;
            }
        }
    } else {
        const float* gg = (s == 0) ? qn_g : kn_g;
        const float* bb = (s == 0) ? qn_b : kn_b;
        float gv[4], bv[4];
#pragma unroll
        for (int ni = 0; ni < 4; ++ni) { gv[ni] = gg[ni * 16 + l15]; bv[ni] = bb[ni * 16 + l15]; }
#pragma unroll
        for (int mi = 0; mi < 4; ++mi) {
#pragma unroll
            for (int j = 0; j < 4; ++j) {
                float v[4];
                float sm = 0.f, sq = 0.f;
#pragma unroll
                for (int ni = 0; ni < 4; ++ni) {
                    v[ni] = acc[mi][ni][j] + qkvb[ni];
                    sm += v[ni];
                    sq += v[ni] * v[ni];
                }
#pragma unroll
                for (int msk = 1; msk < 16; msk <<= 1) {
                    sm += __shfl_xor(sm, msk);
                    sq += __shfl_xor(sq, msk);
                }
                float mean = sm * (1.f / 64.f);
                float var  = sq * (1.f / 64.f) - mean * mean;
                float rstd = rsqrtf(var + EPS_);
                int row = m0 + wm * 64 + mi * 16 + lg * 4 + j;
                int bidx = row >> 10, pos = row & 1023;
                if (s == 0) {
                    size_t rbase = ((size_t)(bidx * H_ + hcol) * 1024 + pos) * 64;
#pragma unroll
                    for (int ni = 0; ni < 4; ++ni) {
                        float o = (v[ni] - mean) * rstd * gv[ni] + bv[ni];
                        qo[rbase + ni * 16 + l15] = (_Float16)(o * QS_);
                    }
                } else {
                    int kvblk = pos >> 5, nh = (pos >> 4) & 1, l15R = pos & 15;
                    size_t base2 = ((size_t)(bidx * H_ + hcol) * 32 + kvblk) * 4 + nh * 2;
#pragma unroll
                    for (int ni = 0; ni < 4; ++ni) {
                        float o = (v[ni] - mean) * rstd * gv[ni] + bv[ni];
                        int ks = ni >> 1, lgR = ((ni & 1) << 1) | (l15 >> 3), elem = l15 & 7;
                        ko[(base2 + ks) * 512 + lgR * 128 + l15R * 8 + elem] = (_Float16)o;
                    }
                }
            }
        }
    }
}

// ---------------- flash attention: pure-register; output packed for proj-A ----------
struct KV {
    half8 kf[2][2];   // [nh][ks]
    half8 vf[4];      // [di]
};

__device__ __forceinline__ void ldKV(KV& s, const _Float16* kp, const _Float16* vp, int kvblk) {
    const _Float16* kb = kp + (size_t)kvblk * 2048;
#pragma unroll
    for (int nh = 0; nh < 2; ++nh)
#pragma unroll
        for (int ks = 0; ks < 2; ++ks)
            s.kf[nh][ks] = *(const half8*)(kb + (nh * 2 + ks) * 512);
    const _Float16* vb = vp + (size_t)kvblk * 2048;
#pragma unroll
    for (int di = 0; di < 4; ++di)
        s.vf[di] = *(const half8*)(vb + di * 512);
}

__device__ __forceinline__ void blockKV(const KV& s, const half8 (&qf)[4][2],
                                        f32x4 (&oacc)[4][4], f32x4 (&lacc)[4],
                                        half8 ones) {
#pragma unroll
    for (int mi = 0; mi < 4; ++mi) {
        f32x4 a0 = {}, a1 = {};
#pragma unroll
        for (int ks = 0; ks < 2; ++ks) {
            a0 = __builtin_amdgcn_mfma_f32_16x16x32_f16(s.kf[0][ks], qf[mi][ks], a0, 0, 0, 0);
            a1 = __builtin_amdgcn_mfma_f32_16x16x32_f16(s.kf[1][ks], qf[mi][ks], a1, 0, 0, 0);
        }
        half8 pf;
#pragma unroll
        for (int j = 0; j < 4; ++j) {
            pf[j]     = (_Float16)exp2_fast(a0[j]);
            pf[j + 4] = (_Float16)exp2_fast(a1[j]);
        }
        lacc[mi] = __builtin_amdgcn_mfma_f32_16x16x32_f16(ones, pf, lacc[mi], 0, 0, 0);
#pragma unroll
        for (int di = 0; di < 4; ++di)
            oacc[mi][di] = __builtin_amdgcn_mfma_f32_16x16x32_f16(s.vf[di], pf, oacc[mi][di], 0, 0, 0);
    }
}

__global__ __launch_bounds__(128, 2) void attn(const _Float16* __restrict__ qg,
                                               const _Float16* __restrict__ kg,
                                               const _Float16* __restrict__ vtg,
                                               _Float16* __restrict__ op) {
    int bphys = blockIdx.x;                          // 0..1535
    int jj = (bphys & 7) * 192 + (bphys >> 3);       // XCD swizzle
    int bh = jj >> 3, qt = jj & 7;
    int b = bh / H_, h = bh % H_;
    int tid = threadIdx.x;
    int wid = tid >> 6, lane = tid & 63;
    int lg = lane >> 4, l15 = lane & 15;
    size_t base = (size_t)bh << 10;
    int qw0 = qt * 128 + wid * 64;

    const _Float16* qrow = qg + (base + qw0 + l15) * 64 + lg * 8;
    half8 qf[4][2];
#pragma unroll
    for (int mi = 0; mi < 4; ++mi)
#pragma unroll
        for (int ks = 0; ks < 2; ++ks)
            qf[mi][ks] = *(const half8*)(qrow + mi * 1024 + ks * 32);

    const _Float16* kp = kg + (size_t)bh * 65536 + lane * 8;
    const _Float16* vp = vtg + (size_t)bh * 65536 + lane * 8;

    half8 ones;
#pragma unroll
    for (int i = 0; i < 8; ++i) ones[i] = (_Float16)1.0f;

    f32x4 oacc[4][4] = {};
    f32x4 lacc[4] = {};

    KV s0, s1;
    ldKV(s0, kp, vp, 0);
    for (int t = 0; t < 16; ++t) {
        ldKV(s1, kp, vp, (2 * t + 1) & 31);
        blockKV(s0, qf, oacc, lacc, ones);
        ldKV(s0, kp, vp, (2 * t + 2) & 31);
        blockKV(s1, qf, oacc, lacc, ones);
    }

    // write O packed as gemm_proj A-fragments: k = 64h + di*16 + lg*4 + j
#pragma unroll
    for (int mi = 0; mi < 4; ++mi) {
        float inv = 1.f / lacc[mi][0];
        int mt = b * 64 + (qw0 >> 4) + mi;
#pragma unroll
        for (int di = 0; di < 4; ++di) {
            half4 h4;
#pragma unroll
            for (int j = 0; j < 4; ++j) h4[j] = (_Float16)(oacc[mi][di][j] * inv);
            *(half4*)&op[pk(mt, 2 * h + (di >> 1), (di & 1) * 2 + (lg >> 1), l15, (lg & 1) * 4)] = h4;
        }
    }
}

// ---------------- proj GEMM: pure-register, depth-2 prefetch, L2-resident A panel --------
__global__ __launch_bounds__(256, 3) void gemm_proj(const _Float16* __restrict__ Ap,
                                                    const _Float16* __restrict__ Bp,
                                                    const float* __restrict__ bias,
                                                    float* __restrict__ out) {
    int xcd = blockIdx.x & 7, loc = blockIdx.x >> 3;     // 768 = 8 * (16 m * 6 n)
    int mt0 = (xcd * 16 + (loc & 15)) * 8;               // m fastest within XCD
    int nt0 = (loc >> 4) * 8;
    int tid = threadIdx.x;
    int wave = tid >> 6, lane = tid & 63;
    int wm = wave >> 1, wn = wave & 1;
    int lg = lane >> 4, l15 = lane & 15;

    const _Float16* pa[4];
    const _Float16* pb[4];
#pragma unroll
    for (int i = 0; i < 4; ++i) {
        pa[i] = Ap + (size_t)(mt0 + wm * 4 + i) * 12288 + lane * 8;
        pb[i] = Bp + (size_t)(nt0 + wn * 4 + i) * 12288 + lane * 8;
    }
    f32x4 acc[4][4] = {};
    half8 a0[4], b0[4], a1[4], b1[4], a2[4], b2[4];
    auto ld = [&](half8 (&a)[4], half8 (&b)[4], int t) {
        int off = t * 512;
#pragma unroll
        for (int i = 0; i < 4; ++i) {
            a[i] = *(const half8*)(pa[i] + off);
            b[i] = *(const half8*)(pb[i] + off);
        }
    };
    auto mm = [&](half8 (&a)[4], half8 (&b)[4]) {
#pragma unroll
        for (int mi = 0; mi < 4; ++mi)
#pragma unroll
            for (int ni = 0; ni < 4; ++ni)
                acc[mi][ni] = __builtin_amdgcn_mfma_f32_16x16x32_f16(a[mi], b[ni], acc[mi][ni], 0, 0, 0);
    };
    ld(a0, b0, 0); ld(a1, b1, 1);
    for (int tt = 0; tt < 8; ++tt) {
        ld(a2, b2, 3 * tt + 2);
        mm(a0, b0);
        if (tt < 7) ld(a0, b0, 3 * tt + 3);
        mm(a1, b1);
        if (tt < 7) ld(a1, b1, 3 * tt + 4);
        mm(a2, b2);
    }

    int m0 = mt0 * 16, n0 = nt0 * 16;
#pragma unroll
    for (int mi = 0; mi < 4; ++mi)
#pragma unroll
        for (int ni = 0; ni < 4; ++ni) {
            int col = n0 + wn * 64 + ni * 16 + l15;
            float bv = bias[col];
#pragma unroll
            for (int j = 0; j < 4; ++j) {
                int row = m0 + wm * 64 + mi * 16 + lg * 4 + j;
                out[(size_t)row * D_ + col] = acc[mi][ni][j] + bv;
            }
        }
}

// ---------------- launch ----------------
extern "C" void kernel_launch(void* const* d_in, const int* in_sizes, int n_in,
                              void* d_out, int out_size, void* d_ws, size_t ws_size,
                              hipStream_t stream) {
    const float* x      = (const float*)d_in[0];
    const float* ln_g   = (const float*)d_in[1];
    const float* ln_b   = (const float*)d_in[2];
    const float* W_qkv  = (const float*)d_in[3];
    const float* b_qkv  = (const float*)d_in[4];
    const float* qn_g   = (const float*)d_in[5];
    const float* qn_b   = (const float*)d_in[6];
    const float* kn_g   = (const float*)d_in[7];
    const float* kn_b   = (const float*)d_in[8];
    const float* W_proj = (const float*)d_in[9];
    const float* b_proj = (const float*)d_in[10];
    float* out = (float*)d_out;
    char* ws = (char*)d_ws;

    constexpr size_t XN_SZ    = (size_t)M_ * D_ * 2;
    constexpr size_t WQKVT_SZ = (size_t)QKVN_ * D_ * 2;
    constexpr size_t WPROJT_SZ= (size_t)D_ * D_ * 2;
    constexpr size_t HEAD_SZ  = (size_t)B_ * H_ * N_ * 64 * 2;

    _Float16* xn_p   = (_Float16*)(ws);                      // A-frag-packed LN(x); reused as ao_p
    _Float16* wqkv_p = (_Float16*)(ws + XN_SZ);
    _Float16* wproj_p= (_Float16*)(ws + XN_SZ + WQKVT_SZ);
    _Float16* qb     = (_Float16*)(ws + XN_SZ + WQKVT_SZ + WPROJT_SZ);
    _Float16* kb     = (_Float16*)((char*)qb + HEAD_SZ);     // K fragment-major
    _Float16* vtb    = (_Float16*)((char*)kb + HEAD_SZ);     // V fragment-major
    _Float16* ao_p   = xn_p;                                 // xn dead after gemm_qkv

    convert_w<<<576, 256, 0, stream>>>(W_qkv, W_proj, wqkv_p, wproj_p);
    ln_embed<<<M_, 256, 0, stream>>>(x, ln_g, ln_b, xn_p);
    gemm_qkv<<<M_ / 128 * (QKVN_ / 128), 256, 0, stream>>>(xn_p, wqkv_p, b_qkv,
                                                           qn_g, qn_b, kn_g, kn_b,
                                                           qb, kb, vtb);
    attn<<<B_ * H_ * (N_ / 128), 128, 0, stream>>>(qb, kb, vtb, ao_p);
    gemm_proj<<<M_ / 128 * (D_ / 128), 256, 0, stream>>>(ao_p, wproj_p, b_proj, out);
}